// Round 2
// baseline (192.849 us; speedup 1.0000x reference)
//
#include <hip/hip_runtime.h>

// SpikeFP32Exp: per pixel (1024*1024), 32 floats in {0,1} encode an fp32 bit
// pattern. Reference collapses to: s = (E + 129) & 255 (E = exponent bits
// x[1..8] MSB-first); u = 16 | mantissa-nibble x[9..12]; output 5 bits of
// V = (s<=4) ? u >> (4-s) : 0, MSB-first.
//
// R1 lesson: direct per-pixel addressing (128 B lane stride loads, 20 B lane
// stride stores) is transaction-limited (~190 us). This version stages both
// sides through LDS so every global access is a coalesced float4.

constexpr int PPB = 256;   // pixels per block (= blockDim.x)
constexpr int INS = 17;    // padded LDS row stride in floats (gcd(17,32)=1)

__global__ __launch_bounds__(256) void spike_kernel(
    const float* __restrict__ x, float* __restrict__ out, int npix) {
    __shared__ float sin_[PPB * INS];   // 17408 B: first 16 words of each pixel
    __shared__ float sout[PPB * 5];     // 5120 B: 5 output floats per pixel

    const int t = threadIdx.x;
    const int pix0 = blockIdx.x * PPB;

    // ---- Stage: first 64 B (4 float4) of each pixel, coalesced reads ----
    // j = pl*4 + q enumerates the 1024 quarters. Wave lanes walk consecutive
    // quarters: 16 pixels x 64 B contiguous chunks -> full 64 B transactions.
    const float4* __restrict__ x4 = reinterpret_cast<const float4*>(x);
    #pragma unroll
    for (int c = 0; c < 4; ++c) {
        int j = c * 256 + t;
        int pl = j >> 2, q = j & 3;
        int pg = pix0 + pl;
        float4 v = (pg < npix) ? x4[(size_t)pg * 8 + q]
                               : make_float4(0.f, 0.f, 0.f, 0.f);
        float* d = sin_ + pl * INS + q * 4;   // scalar writes: ~2 lanes/bank
        d[0] = v.x; d[1] = v.y; d[2] = v.z; d[3] = v.w;
    }
    __syncthreads();

    // ---- Compute: one pixel per thread from LDS ----
    {
        const float* w = sin_ + t * INS;      // stride 17 -> 2-way, free
        unsigned E = 0;
        E |= (unsigned)(w[1]  != 0.f) << 7;
        E |= (unsigned)(w[2]  != 0.f) << 6;
        E |= (unsigned)(w[3]  != 0.f) << 5;
        E |= (unsigned)(w[4]  != 0.f) << 4;
        E |= (unsigned)(w[5]  != 0.f) << 3;
        E |= (unsigned)(w[6]  != 0.f) << 2;
        E |= (unsigned)(w[7]  != 0.f) << 1;
        E |= (unsigned)(w[8]  != 0.f);
        unsigned M = 0;
        M |= (unsigned)(w[9]  != 0.f) << 3;
        M |= (unsigned)(w[10] != 0.f) << 2;
        M |= (unsigned)(w[11] != 0.f) << 1;
        M |= (unsigned)(w[12] != 0.f);

        unsigned s = (E + 129u) & 255u;       // (E - 127) mod 256
        unsigned u = 16u | M;                 // 1.mmmm as 5-bit int
        unsigned V = (s <= 4u) ? (u >> (4u - s)) : 0u;

        float* o = sout + t * 5;              // stride 5: conflict-free
        o[0] = (float)((V >> 4) & 1u);
        o[1] = (float)((V >> 3) & 1u);
        o[2] = (float)((V >> 2) & 1u);
        o[3] = (float)((V >> 1) & 1u);
        o[4] = (float)( V       & 1u);
    }
    __syncthreads();

    // ---- Flush: 320 contiguous float4 stores per block, coalesced ----
    const float4* s4 = reinterpret_cast<const float4*>(sout);
    float4* o4 = reinterpret_cast<float4*>(out) + (size_t)pix0 * 5 / 4;
    size_t nq4_total = ((size_t)npix * 5) / 4;
    size_t base = (size_t)pix0 * 5 / 4;
    if (base + t < nq4_total)       o4[t]       = s4[t];
    if (t < 64 && base + 256 + t < nq4_total) o4[256 + t] = s4[256 + t];
}

extern "C" void kernel_launch(void* const* d_in, const int* in_sizes, int n_in,
                              void* d_out, int out_size, void* d_ws, size_t ws_size,
                              hipStream_t stream) {
    const float* x = (const float*)d_in[0];
    float* out = (float*)d_out;
    int npix = in_sizes[0] / 32;
    int grid = (npix + PPB - 1) / PPB;
    spike_kernel<<<grid, 256, 0, stream>>>(x, out, npix);
}

// Round 3
// 190.774 us; speedup vs baseline: 1.0109x; 1.0109x over previous
//
#include <hip/hip_runtime.h>

// SpikeFP32Exp: per pixel (1024*1024), 32 floats in {0,1} encode an fp32 bit
// pattern. Collapses to: E = exponent bits x[1..8] (MSB first),
// M = mantissa nibble x[9..12], s = (E+129)&255, u = 16|M,
// V = (s<=4) ? u >> (4-s) : 0, emitted as 5 floats MSB-first.
//
// R1 (direct strided) == R2 (fully LDS-staged) == ~191 us total, and
// spike_kernel never appears in rocprof top-5 (all 78 us, 512 MiB harness
// poison fills) -> kernel < 78 us, dur_us dominated by fixed harness work.
// R3: leanest version (direct sector loads, output-only LDS staging,
// grid-stride, 1024 blocks) to confirm the kernel is at its traffic floor.

constexpr int PPB = 256;   // pixels per tile (= blockDim.x)

__global__ __launch_bounds__(256, 8) void spike_kernel(
    const float* __restrict__ x, float* __restrict__ out, int ntiles) {
    __shared__ float sout[PPB * 5];
    const int t = threadIdx.x;

    for (int tile = blockIdx.x; tile < ntiles; tile += gridDim.x) {
        const int pix = tile * PPB + t;

        // Direct load of the first 64 B (one sector) of this pixel's 128 B
        // record. All 4 float4s hit the same 64 B sector -> no extra lines.
        const float4* __restrict__ xb =
            reinterpret_cast<const float4*>(x) + (size_t)pix * 8;
        float4 w0 = xb[0];  // words 0..3   (word0 = sign, unused)
        float4 w1 = xb[1];  // words 4..7
        float4 w2 = xb[2];  // words 8..11
        float4 w3 = xb[3];  // words 12..15 (only word12 used)

        unsigned E = 0;
        E |= (unsigned)(w0.y != 0.f) << 7;
        E |= (unsigned)(w0.z != 0.f) << 6;
        E |= (unsigned)(w0.w != 0.f) << 5;
        E |= (unsigned)(w1.x != 0.f) << 4;
        E |= (unsigned)(w1.y != 0.f) << 3;
        E |= (unsigned)(w1.z != 0.f) << 2;
        E |= (unsigned)(w1.w != 0.f) << 1;
        E |= (unsigned)(w2.x != 0.f);
        unsigned M = 0;
        M |= (unsigned)(w2.y != 0.f) << 3;
        M |= (unsigned)(w2.z != 0.f) << 2;
        M |= (unsigned)(w2.w != 0.f) << 1;
        M |= (unsigned)(w3.x != 0.f);

        unsigned s = (E + 129u) & 255u;   // (E - 127) mod 256
        unsigned u = 16u | M;             // 1.mmmm as 5-bit int
        unsigned V = (s <= 4u) ? (u >> (4u - s)) : 0u;

        float* o = sout + t * 5;          // stride 5: conflict-free
        o[0] = (float)((V >> 4) & 1u);
        o[1] = (float)((V >> 3) & 1u);
        o[2] = (float)((V >> 2) & 1u);
        o[3] = (float)((V >> 1) & 1u);
        o[4] = (float)( V       & 1u);
        __syncthreads();

        // Flush 320 contiguous float4 per tile: fully coalesced stores.
        const float4* s4 = reinterpret_cast<const float4*>(sout);
        float4* o4 = reinterpret_cast<float4*>(out) + (size_t)tile * PPB * 5 / 4;
        o4[t] = s4[t];
        if (t < 64) o4[256 + t] = s4[256 + t];
        __syncthreads();   // sout reused next tile
    }
}

extern "C" void kernel_launch(void* const* d_in, const int* in_sizes, int n_in,
                              void* d_out, int out_size, void* d_ws, size_t ws_size,
                              hipStream_t stream) {
    const float* x = (const float*)d_in[0];
    float* out = (float*)d_out;
    int npix = in_sizes[0] / 32;          // 1048576, divisible by PPB
    int ntiles = npix / PPB;              // 4096
    int grid = 1024;                      // 4 tiles per block, grid-stride
    spike_kernel<<<grid, 256, 0, stream>>>(x, out, ntiles);
}